// Round 9
// baseline (301.533 us; speedup 1.0000x reference)
//
#include <hip/hip_runtime.h>
#include <math.h>

#define S      512
#define BATCH  32
#define NGRP   256           // diagonal groups of 4: p in [0,1023) -> p>>2 in [0,256)
#define LDSP   68
#define INFF   __builtin_huge_valf()
#define KNEG   (-(1 << 28))  // scale of an exact-zero (INF cost) value
#define MEXP   185           // e^c == 2^MEXP exactly; c = 185*ln2 ~ 128.24

// wave-wide shift-up-by-1 via DPP wave_shr:1 (VALU, no DS pipe).
// lane i gets src[i-1]; lane 0 gets old's lane-0 value (bound_ctrl=false). [HW-verified]
__device__ __forceinline__ float dpp_shr1(float src, float old) {
    return __int_as_float(__builtin_amdgcn_update_dpp(
        __float_as_int(old), __float_as_int(src), 0x138, 0xf, 0xf, false));
}
__device__ __forceinline__ int dpp_shr1_i(int src, int old) {
    return __builtin_amdgcn_update_dpp(old, src, 0x138, 0xf, 0xf, false);
}
// full-wave rotate: lane i gets src[(i-1)&63] (lane 0 <- lane 63). [HW-verified]
__device__ __forceinline__ float dpp_ror1(float src) {
    return __int_as_float(__builtin_amdgcn_update_dpp(
        0, __float_as_int(src), 0x13C, 0xf, 0xf, false));
}
__device__ __forceinline__ int dpp_ror1_i(int src) {
    return __builtin_amdgcn_update_dpp(0, src, 0x13C, 0xf, 0xf, false);
}
__device__ __forceinline__ float lane_bcast(float v, int l) {
    return __int_as_float(__builtin_amdgcn_readlane(__float_as_int(v), l));
}
__device__ __forceinline__ int lane_bcast_i(int v, int l) {
    return __builtin_amdgcn_readlane(v, l);
}

// ---------------------------------------------------------------------------
// Kernel 1: D[b,i,j] = |x_i|^2 + |y_j|^2 - 2<x_i,y_j>, stored in 4-wide
// diagonal groups:  ws[b][p>>2][i][p&3]  with p = i + j.  (unchanged)
// ---------------------------------------------------------------------------
__global__ __launch_bounds__(256) void pairdist_kernel(
    const float* __restrict__ X, const float* __restrict__ Y,
    float* __restrict__ Dd)
{
    const int b   = blockIdx.z;
    const int i0  = blockIdx.y * 64;
    const int j0  = blockIdx.x * 64;
    const int tid = threadIdx.x;

    __shared__ float smem[64 * LDSP * 2];
    __shared__ float x2s[64], y2s[64];
    float* XsT = smem;
    float* YsT = smem + 64 * LDSP;

    const float* Xb = X + ((size_t)b * S + i0) * 64;
    const float* Yb = Y + ((size_t)b * S + j0) * 64;

#pragma unroll
    for (int c = 0; c < 4; ++c) {
        int idx = c * 1024 + tid * 4;
        int row = idx >> 6;
        int k   = idx & 63;
        float4 vx = *(const float4*)(Xb + (size_t)row * 64 + k);
        float4 vy = *(const float4*)(Yb + (size_t)row * 64 + k);
        XsT[(k + 0) * LDSP + row] = vx.x; XsT[(k + 1) * LDSP + row] = vx.y;
        XsT[(k + 2) * LDSP + row] = vx.z; XsT[(k + 3) * LDSP + row] = vx.w;
        YsT[(k + 0) * LDSP + row] = vy.x; YsT[(k + 1) * LDSP + row] = vy.y;
        YsT[(k + 2) * LDSP + row] = vy.z; YsT[(k + 3) * LDSP + row] = vy.w;
    }
    __syncthreads();

    if (tid < 64) {
        float s = 0.f;
#pragma unroll 8
        for (int k = 0; k < 64; ++k) { float v = XsT[k * LDSP + tid]; s = fmaf(v, v, s); }
        x2s[tid] = s;
    } else if (tid < 128) {
        int r = tid - 64;
        float s = 0.f;
#pragma unroll 8
        for (int k = 0; k < 64; ++k) { float v = YsT[k * LDSP + r]; s = fmaf(v, v, s); }
        y2s[r] = s;
    }
    __syncthreads();

    const int tx = tid & 15;
    const int ty = tid >> 4;
    float acc[4][4] = {};
#pragma unroll 4
    for (int k = 0; k < 64; ++k) {
        float4 a  = *(const float4*)&XsT[k * LDSP + ty * 4];
        float4 bb = *(const float4*)&YsT[k * LDSP + tx * 4];
        float av[4] = {a.x, a.y, a.z, a.w};
        float bv[4] = {bb.x, bb.y, bb.z, bb.w};
#pragma unroll
        for (int r = 0; r < 4; ++r)
#pragma unroll
            for (int c = 0; c < 4; ++c)
                acc[r][c] = fmaf(av[r], bv[c], acc[r][c]);
    }

    float xr[4], yc[4];
#pragma unroll
    for (int r = 0; r < 4; ++r) xr[r] = x2s[ty * 4 + r];
#pragma unroll
    for (int c = 0; c < 4; ++c) yc[c] = y2s[tx * 4 + c];

    float vout[4][4];
#pragma unroll
    for (int r = 0; r < 4; ++r)
#pragma unroll
        for (int c = 0; c < 4; ++c)
            vout[r][c] = xr[r] + yc[c] - 2.0f * acc[r][c];

    __syncthreads();

    float* diag = smem;
#pragma unroll
    for (int r = 0; r < 4; ++r) {
        int il = ty * 4 + r;
#pragma unroll
        for (int cc = 0; cc < 4; ++cc) {
            int c   = (cc + tx + ty) & 3;
            float v = vout[r][0];
            v = (c == 1) ? vout[r][1] : v;
            v = (c == 2) ? vout[r][2] : v;
            v = (c == 3) ? vout[r][3] : v;
            int jl = tx * 4 + c;
            diag[il * 128 + jl] = v;
        }
    }
    __syncthreads();

    const int w     = tid >> 6;
    const int il    = tid & 63;
    const int gbase = (i0 + j0) >> 2;
    float* dstB = Dd + (size_t)b * (NGRP * S * 4);
#pragma unroll
    for (int t = 0; t < 8; ++t) {
        int gl   = w + 4 * t;
        int joff = 4 * gl - il;
        float c0 = diag[il * 127 + 4 * gl + 0];
        float c1 = diag[il * 127 + 4 * gl + 1];
        float c2 = diag[il * 127 + 4 * gl + 2];
        float c3 = diag[il * 127 + 4 * gl + 3];
        size_t base = ((size_t)(gbase + gl) * S + (i0 + il)) * 4;
        if (joff >= 0 && joff <= 60) {
            float4 v; v.x = c0; v.y = c1; v.z = c2; v.w = c3;
            *(float4*)(dstB + base) = v;
        } else {
            if ((unsigned)(joff + 0) <= 63u) dstB[base + 0] = c0;
            if ((unsigned)(joff + 1) <= 63u) dstB[base + 1] = c1;
            if ((unsigned)(joff + 2) <= 63u) dstB[base + 2] = c2;
            if ((unsigned)(joff + 3) <= 63u) dstB[base + 3] = c3;
        }
    }
}

// ---------------------------------------------------------------------------
// Kernel 2 (v9): EXP-SPACE staggered soft-DTW DP on the verified v5 skeleton.
// Identity: e^{-R} = e^{-D} (e^{-R_dd} + e^{-R_up} + e^{-R_lf}) — linear in
// E = e^{-R}. Lane state (V,k): E*e^{c*p} = V*2^k, V in [1,2) or 0 (INF cost),
// invariant V==0 => k ~ KNEG. Per cell: align the 3 terms to km = max scale
// (ldexp shifts <= 0: exact, no overflow; dropped bits = negligible softmin
// terms, same as reference's exp(m-x) underflow), sum, multiply by
// wf = exp2(frac(185 - D*log2e)) in [0.7,1.42], renorm via mantissa bit-ops
// (Vn in [0.7,8.7] or exact 0 — never denormal/inf/nan). e^c = 2^185 folds
// into dd's integer shift; 2^ti (power part of e^{c-D}) folds into k.
// NO transcendental in the serial chain (exp2 depends only on prefetched D).
// Structure = v5 (bit-exact-verified): 8 waves, strip = 2*(w&3)+(w>>2),
// 64-row strips, stagger 2, 23 super-steps, double-buffered ring + extra
// (now carrying V,k pairs). Window 0 head-pred; window 8 tail-pred (freezes
// lanes past j=511 — replaces v5's bank-parity output protection).
// Final: R = ln2*(185*1022 - k) - ln(V), computed once in double.
// NOTE: not bit-exact vs reference (first deviation this session; expected
// absmax ~ the reference's own fp32 rounding noise, ~1e-1 at |R|~5e4).
// ---------------------------------------------------------------------------
__global__ __launch_bounds__(512) void softdtw_dp_exp(
    const float* __restrict__ Dd, float* __restrict__ out)
{
    const int b     = blockIdx.x;
    const int tid   = threadIdx.x;
    const int w     = tid >> 6;
    const int lane  = tid & 63;
    const int strip = 2 * (w & 3) + (w >> 2);   // SIMD-pairing permutation

    __shared__ float ringV[7][2][64];
    __shared__ int   ringK[7][2][64];
    __shared__ float extraV[7][2];
    __shared__ int   extraK[7][2];

    const float4* __restrict__ Dbat =
        (const float4*)(Dd + (size_t)b * (NGRP * S * 4));

    const int  i0   = 64 * strip + lane;     // this lane's matrix row i
    const bool is63 = (lane == 63);

    float V = 0.0f;   int k  = KNEG;    // own cell (diag p-1): INF seed
    float u = 0.0f;   int kd = KNEG;    // dd carry: neighbor value at p-2, scale+MEXP
    float tsV = 0.0f; int tsK = KNEG;   // boundary stream registers
    float taccV = 0.0f; int taccK = KNEG;
    float lastV = 0.0f; int lastK = KNEG;
    float4 Q[4];
    int qg = 0;

    // one exp-space DP step. PRED(kk) may override Vnew/knew with old V,k.
#define STEP(QC, PRED, kk)                                                \
    {                                                                     \
        float t  = fmaf(-1.44269504f, (QC), 185.0f);  /* out of chain */  \
        float fr = rintf(t);                                              \
        int   ti = (int)fr;                                               \
        float wf = exp2f(t - fr);                                         \
        float Vs = dpp_shr1(V, tsV);        /* lane0 <- stream */         \
        int   ks = dpp_shr1_i(k, tsK);                                    \
        tsV = dpp_ror1(tsV);  tsK = dpp_ror1_i(tsK);                      \
        int km = max(k, max(ks, kd));                                     \
        float a = ldexpf(V, k - km) + ldexpf(Vs, ks - km)                 \
                + ldexpf(u, kd - km);                                     \
        float Vn = wf * a;                  /* in [0.7,8.7] or exact 0 */ \
        unsigned bi = __float_as_uint(Vn);                                \
        bool  z  = (Vn == 0.0f);                                          \
        int   e  = (int)(bi >> 23) - 127;                                 \
        float Vm = __uint_as_float((bi & 0x007FFFFFu) | 0x3F800000u);     \
        float Vnew = z ? 0.0f : Vm;                                       \
        int   knew = z ? KNEG : (km + e + ti);                            \
        PRED(kk)                                                          \
        V = Vnew;  k = knew;                                              \
        u = Vs;    kd = ks + MEXP;          /* KNEG+MEXP still ~KNEG */   \
        taccV = dpp_ror1(is63 ? V : taccV);                               \
        taccK = dpp_ror1_i(is63 ? k : taccK);                             \
    }

#define P_NONE(kk)
#define P_HEAD(kk)  Vnew = (lane <= (kk)) ? Vnew : V;                     \
                    knew = (lane <= (kk)) ? knew : k;
#define P_TAIL(kk)  Vnew = (lane >  (kk)) ? Vnew : V;                     \
                    knew = (lane >  (kk)) ? knew : k;

    // 4 steps = one D group
#define GIT(Qi, PRED, kk)                                                 \
    {                                                                     \
        float4 q = Q[Qi];                                                 \
        int gq = qg + 4; gq = (gq > 255) ? 255 : gq;                      \
        Q[Qi] = *(Dbat + (size_t)gq * S + i0);                            \
        qg += 1;                                                          \
        STEP(q.x, PRED, (kk) + 0)  STEP(q.y, PRED, (kk) + 1)              \
        STEP(q.z, PRED, (kk) + 2)  STEP(q.w, PRED, (kk) + 3)              \
    }

    for (int n = 0; n < 23; ++n) {
        const int na = n - 2 * strip;
        if (0 <= na && na < 9) {
            if (na == 0) {                 // strip-run start: seed dd + queue
                u  = (strip == 0) ? 1.0f : 0.0f;   // corner E*e^{c*(-2)}=2^{-2M}
                kd = (strip == 0) ? -MEXP : KNEG;  // (+M fold) -> -M
                qg = 16 * strip;
#pragma unroll
                for (int i = 0; i < 4; ++i)
                    Q[i] = *(Dbat + (size_t)(qg + i) * S + i0);
            }
            if (strip > 0) {               // boundary stream for this window
                float tV = ringV[strip - 1][(n - 1) & 1][lane];
                int   tK = ringK[strip - 1][(n - 1) & 1][lane];
                float eV = extraV[strip - 1][(n - 1) & 1];
                int   eK = extraK[strip - 1][(n - 1) & 1];
                tsV = (lane == 0) ? eV : tV;
                tsK = (lane == 0) ? eK : tK;
            } else {
                tsV = 0.0f;  tsK = KNEG;   // INF wall for strip 0
            }

            if (na == 0) {                 // head: active iff lane <= step
#pragma unroll
                for (int it = 0; it < 4; ++it) {
                    const int kk = 16 * it;
                    GIT(0, P_HEAD, kk)      GIT(1, P_HEAD, kk + 4)
                    GIT(2, P_HEAD, kk + 8)  GIT(3, P_HEAD, kk + 12)
                }
            } else if (na == 8) {          // tail: freeze lanes past j=511
#pragma unroll
                for (int it = 0; it < 4; ++it) {
                    const int kk = 16 * it;
                    GIT(0, P_TAIL, kk)      GIT(1, P_TAIL, kk + 4)
                    GIT(2, P_TAIL, kk + 8)  GIT(3, P_TAIL, kk + 12)
                }
            } else {                       // hot path (7 windows)
#pragma unroll 1
                for (int it = 0; it < 4; ++it) {
                    GIT(0, P_NONE, 0) GIT(1, P_NONE, 0)
                    GIT(2, P_NONE, 0) GIT(3, P_NONE, 0)
                }
            }

            if (strip < 7) {               // publish boundary (V,k) block
                ringV[strip][n & 1][lane] = taccV;
                ringK[strip][n & 1][lane] = taccK;
                if (lane == 0) {
                    extraV[strip][n & 1] = lastV;
                    extraK[strip][n & 1] = lastK;
                }
                lastV = lane_bcast(taccV, 0);
                lastK = lane_bcast_i(taccK, 0);
            }
        }
        __syncthreads();
    }
#undef GIT
#undef P_TAIL
#undef P_HEAD
#undef P_NONE
#undef STEP

    // R(511,511): strip 7 (wave 7), lane 63; p = 1022, M*p = 185*1022 = 189070
    if (tid == 511)
        out[b] = (float)(0.6931471805599453 * (double)(189070 - k)
                         - log((double)V));
}

// ---------------------------------------------------------------------------
extern "C" void kernel_launch(void* const* d_in, const int* in_sizes, int n_in,
                              void* d_out, int out_size, void* d_ws, size_t ws_size,
                              hipStream_t stream)
{
    const float* X = (const float*)d_in[0];
    const float* Y = (const float*)d_in[1];
    float* out = (float*)d_out;
    float* Dd  = (float*)d_ws;   // 32 * 256*512*4 floats = 64 MiB

    dim3 g1(S / 64, S / 64, BATCH);
    pairdist_kernel<<<g1, 256, 0, stream>>>(X, Y, Dd);

    softdtw_dp_exp<<<BATCH, 512, 0, stream>>>(Dd, out);
}

// Round 11
// 276.004 us; speedup vs baseline: 1.0925x; 1.0925x over previous
//
#include <hip/hip_runtime.h>
#include <math.h>

#define S      512
#define BATCH  32
#define NGRP   256           // diagonal groups of 4: p in [0,1023) -> p>>2 in [0,256)
#define INFF   __builtin_huge_valf()

// wave-wide shift-up-by-1 via DPP wave_shr:1 (VALU, no DS pipe).
// lane i gets src[i-1]; lane 0 gets old's lane-0 value (bound_ctrl=false). [HW-verified]
__device__ __forceinline__ float dpp_shr1(float src, float old) {
    return __int_as_float(__builtin_amdgcn_update_dpp(
        __float_as_int(old), __float_as_int(src), 0x138, 0xf, 0xf, false));
}

// full-wave rotate: lane i gets src[(i-1)&63] (lane 0 <- lane 63). [HW-verified]
__device__ __forceinline__ float dpp_ror1(float src) {
    return __int_as_float(__builtin_amdgcn_update_dpp(
        0, __float_as_int(src), 0x13C, 0xf, 0xf, false));
}

__device__ __forceinline__ float lane_bcast(float v, int l) {
    return __int_as_float(__builtin_amdgcn_readlane(__float_as_int(v), l));
}

// ---------------------------------------------------------------------------
// Kernel 1 (v10): 128x128-tile pairdist. D[b,i,j] = |x_i|^2+|y_j|^2-2<x_i,y_j>
// stored diag-grouped ws[b][p>>2][i][p&3], p = i+j (same layout as before).
// 512 blocks x 256 threads; 64 outputs/thread (rows ty*4+r and 64+ty*4+r,
// cols tx*8+c) -> ds_read:FMA = 1:16 (vs 1:8 at 64-tile), input re-reads
// halved. Diag staging reuses the XsT/YsT LDS (aliased) in two 64-row
// passes; stride 260 floats => b128 reads 16B-aligned + bank-disjoint.
// Per-cell expression and k-ascending fmaf order unchanged -> bit-exact.
// ---------------------------------------------------------------------------
#define XST  132              // [k][i] stride for 128-wide tiles
#define DST  260              // diag row stride (aligned reads, 2-way writes)

__global__ __launch_bounds__(256) void pairdist128(
    const float* __restrict__ X, const float* __restrict__ Y,
    float* __restrict__ Dd)
{
    const int b   = blockIdx.z;
    const int i0  = blockIdx.y * 128;
    const int j0  = blockIdx.x * 128;
    const int tid = threadIdx.x;

    __shared__ __align__(16) float smem[2 * 64 * XST];  // XsT|YsT, then diag
    __shared__ float x2s[128], y2s[128];
    float* XsT  = smem;              // [k][i], i < 128
    float* YsT  = smem + 64 * XST;   // [k][j], j < 128
    float* diag = smem;              // [il][p_local], stride DST (aliased)

    const float* Xb = X + ((size_t)b * S + i0) * 64;
    const float* Yb = Y + ((size_t)b * S + j0) * 64;

    // stage 128 rows x 64 dims of X and Y, transposed to [k][row]
#pragma unroll
    for (int c = 0; c < 8; ++c) {
        int idx = c * 1024 + tid * 4;
        int row = idx >> 6;          // 0..127
        int k   = idx & 63;          // multiple of 4
        float4 vx = *(const float4*)(Xb + (size_t)row * 64 + k);
        float4 vy = *(const float4*)(Yb + (size_t)row * 64 + k);
        XsT[(k + 0) * XST + row] = vx.x; XsT[(k + 1) * XST + row] = vx.y;
        XsT[(k + 2) * XST + row] = vx.z; XsT[(k + 3) * XST + row] = vx.w;
        YsT[(k + 0) * XST + row] = vy.x; YsT[(k + 1) * XST + row] = vy.y;
        YsT[(k + 2) * XST + row] = vy.z; YsT[(k + 3) * XST + row] = vy.w;
    }
    __syncthreads();

    // row/col squared norms (same fmaf chain as before -> bit-exact)
    if (tid < 128) {
        float s = 0.f;
#pragma unroll 8
        for (int k = 0; k < 64; ++k) { float v = XsT[k * XST + tid]; s = fmaf(v, v, s); }
        x2s[tid] = s;
    } else {
        int r = tid - 128;
        float s = 0.f;
#pragma unroll 8
        for (int k = 0; k < 64; ++k) { float v = YsT[k * XST + r]; s = fmaf(v, v, s); }
        y2s[r] = s;
    }
    __syncthreads();

    const int tx = tid & 15;
    const int ty = tid >> 4;
    float acc[8][8] = {};
#pragma unroll 2
    for (int k = 0; k < 64; ++k) {
        float4 a0 = *(const float4*)&XsT[k * XST + ty * 4];
        float4 a1 = *(const float4*)&XsT[k * XST + 64 + ty * 4];
        float4 b0 = *(const float4*)&YsT[k * XST + tx * 8];
        float4 b1 = *(const float4*)&YsT[k * XST + tx * 8 + 4];
        float av[8] = {a0.x, a0.y, a0.z, a0.w, a1.x, a1.y, a1.z, a1.w};
        float bv[8] = {b0.x, b0.y, b0.z, b0.w, b1.x, b1.y, b1.z, b1.w};
#pragma unroll
        for (int r = 0; r < 8; ++r)
#pragma unroll
            for (int c = 0; c < 8; ++c)
                acc[r][c] = fmaf(av[r], bv[c], acc[r][c]);
    }

    // epilogue in place: acc[r][c] -> D value (same expression as before)
    float xr[8], yc[8];
#pragma unroll
    for (int r = 0; r < 4; ++r) { xr[r] = x2s[ty * 4 + r]; xr[4 + r] = x2s[64 + ty * 4 + r]; }
#pragma unroll
    for (int c = 0; c < 8; ++c) yc[c] = y2s[tx * 8 + c];
#pragma unroll
    for (int r = 0; r < 8; ++r)
#pragma unroll
        for (int c = 0; c < 8; ++c)
            acc[r][c] = xr[r] + yc[c] - 2.0f * acc[r][c];

    const int w     = tid >> 6;
    const int il    = tid & 63;
    const int gbase = (i0 + j0) >> 2;
    float* dstB = Dd + (size_t)b * (NGRP * S * 4);

#pragma unroll
    for (int pass = 0; pass < 2; ++pass) {
        __syncthreads();   // XsT/YsT (or previous diag) reads done

        // write this pass's 64 rows into diag[il][p_local]
#pragma unroll
        for (int r = 0; r < 4; ++r) {
            int ilw  = ty * 4 + r;                 // LDS row slot
            int iLoc = pass * 64 + ilw;            // tile-local row
            int base = ilw * DST + iLoc + tx * 8;  // p_local = iLoc + tx*8 + c
#pragma unroll
            for (int c = 0; c < 8; ++c)
                diag[base + c] = acc[pass * 4 + r][c];
        }
        __syncthreads();

        // store phase: wave w -> groups gl = w + 4t; lane = row il
        const int t0 = pass ? 4 : 0;               // B: gl >= 16
        const int t1 = pass ? 16 : 12;             // A: gl <= 47
        const int iLoc = pass * 64 + il;
        for (int t = t0; t < t1; ++t) {
            int gl = w + 4 * t;
            float4 v = *(const float4*)&diag[il * DST + 4 * gl];
            int joff = 4 * gl - iLoc;              // j_local of component 0
            size_t base = ((size_t)(gbase + gl) * S + (i0 + iLoc)) * 4;
            if (joff >= 0 && joff <= 124) {
                *(float4*)(dstB + base) = v;
            } else {
                if ((unsigned)(joff + 0) < 128u) dstB[base + 0] = v.x;
                if ((unsigned)(joff + 1) < 128u) dstB[base + 1] = v.y;
                if ((unsigned)(joff + 2) < 128u) dstB[base + 2] = v.z;
                if ((unsigned)(joff + 3) < 128u) dstB[base + 3] = v.w;
            }
        }
    }
}

// ---------------------------------------------------------------------------
// Kernel 2: v5 verbatim (round-5 measured 195 µs, bit-exact) — 8-wave
// staggered soft-DTW DP, 2 pipeline stages per SIMD, 64-row strips,
// stagger 2, double-buffered reversed ring + extraS handoff, E/O parity
// register banks, window-0 predication, 23 super-steps.
// ---------------------------------------------------------------------------
__global__ __launch_bounds__(512) void softdtw_dp_stag8(
    const float* __restrict__ Dd, float* __restrict__ out)
{
    const int b     = blockIdx.x;
    const int tid   = threadIdx.x;
    const int w     = tid >> 6;
    const int lane  = tid & 63;
    const int strip = 2 * (w & 3) + (w >> 2);   // SIMD-pairing permutation

    __shared__ float ring[7][2][64];   // reversed boundary blocks
    __shared__ float extraS[7][2];     // previous block's last value

    const float4* __restrict__ Dbat =
        (const float4*)(Dd + (size_t)b * (NGRP * S * 4));

    const int  i0   = 64 * strip + lane;     // this lane's row
    const bool is63 = (lane == 63);

    float rE = INFF, rO = INFF;        // even-diag bank, odd-diag bank
    float up_prev = INFF, tshift = INFF, tacc = 0.0f, last_prev = INFF;
    float4 Q[4];
    int qg = 0;                        // group consumed by current GITER

    // one cell: PW = write bank (diag p-2 -> p), CU = other bank (diag p-1)
#define CELL1(PW, CU, qc, PRED, kk)                                      \
    {                                                                    \
        float up = dpp_shr1(CU, tshift);   /* lane0 <- stream(p-1) */    \
        tshift = dpp_ror1(tshift);                                       \
        float dd = up_prev, lf = CU;                                     \
        float mn = fminf(up, fminf(dd, lf));                             \
        float e  = __expf(mn - dd) + __expf(mn - up) + __expf(mn - lf);  \
        float val = (qc) + (mn - __logf(e));                             \
        if (PRED) val = (lane <= (kk)) ? val : PW;                       \
        PW = val;                                                        \
        tacc = dpp_ror1(is63 ? PW : tacc);                               \
        up_prev = up;                                                    \
    }

    // 4 steps = one D group (p0 = multiple of 4 -> parity E,O,E,O static)
#define GITER1(Qi, PRED, kk)                                             \
    {                                                                    \
        float4 q = Q[Qi];                                                \
        int gq = qg + 4; gq = (gq > 255) ? 255 : gq;                     \
        Q[Qi] = *(Dbat + (size_t)gq * S + i0);                           \
        qg += 1;                                                         \
        CELL1(rE, rO, q.x, PRED, (kk) + 0)                               \
        CELL1(rO, rE, q.y, PRED, (kk) + 1)                               \
        CELL1(rE, rO, q.z, PRED, (kk) + 2)                               \
        CELL1(rO, rE, q.w, PRED, (kk) + 3)                               \
    }

    for (int n = 0; n < 23; ++n) {
        const int na = n - 2 * strip;
        if (0 <= na && na < 9) {
            if (na == 0) {                 // strip-run start: seed + queue fill
                up_prev = (strip == 0) ? 0.0f : INFF;   // corner / INF wall
                qg = 16 * strip;
#pragma unroll
                for (int i = 0; i < 4; ++i)
                    Q[i] = *(Dbat + (size_t)(qg + i) * S + i0);
            }
            if (strip > 0) {               // load stream block for this window
                float t  = ring[strip - 1][(n - 1) & 1][lane];
                float ex = extraS[strip - 1][(n - 1) & 1];
                tshift = (lane == 0) ? ex : t;
            } else {
                tshift = INFF;             // R[-1][*] wall for strip 0
            }

            if (na == 0) {                 // predicated window (j >= 0 edge)
#pragma unroll
                for (int it = 0; it < 4; ++it) {
                    const int kk = 16 * it;
                    GITER1(0, true, kk)      GITER1(1, true, kk + 4)
                    GITER1(2, true, kk + 8)  GITER1(3, true, kk + 12)
                }
            } else {                       // hot loop
#pragma unroll 1
                for (int it = 0; it < 4; ++it) {
                    GITER1(0, false, 0) GITER1(1, false, 0)
                    GITER1(2, false, 0) GITER1(3, false, 0)
                }
            }

            if (strip < 7) {               // publish boundary block
                ring[strip][n & 1][lane] = tacc;
                if (lane == 0) extraS[strip][n & 1] = last_prev;
                last_prev = lane_bcast(tacc, 0);   // this window's last value
            }
        }
        __syncthreads();
    }
#undef GITER1
#undef CELL1

    // R[511][511]: strip 7 (wave 7), lane 63, diag 1022 (even bank)
    if (tid == 511) out[b] = rE;
}

// ---------------------------------------------------------------------------
extern "C" void kernel_launch(void* const* d_in, const int* in_sizes, int n_in,
                              void* d_out, int out_size, void* d_ws, size_t ws_size,
                              hipStream_t stream)
{
    const float* X = (const float*)d_in[0];
    const float* Y = (const float*)d_in[1];
    float* out = (float*)d_out;
    float* Dd  = (float*)d_ws;   // 32 * 256*512*4 floats = 64 MiB

    dim3 g1(S / 128, S / 128, BATCH);
    pairdist128<<<g1, 256, 0, stream>>>(X, Y, Dd);

    softdtw_dp_stag8<<<BATCH, 512, 0, stream>>>(Dd, out);
}

// Round 13
// 249.416 us; speedup vs baseline: 1.2090x; 1.1066x over previous
//
#include <hip/hip_runtime.h>
#include <math.h>

#define S      512
#define BATCH  32
#define NGRP   256           // diagonal groups of 4: p in [0,1023) -> p>>2 in [0,256)
#define INFF   __builtin_huge_valf()

// wave-wide shift-up-by-1 via DPP wave_shr:1 (VALU, no DS pipe).
// lane i gets src[i-1]; lane 0 gets old's lane-0 value (bound_ctrl=false). [HW-verified]
__device__ __forceinline__ float dpp_shr1(float src, float old) {
    return __int_as_float(__builtin_amdgcn_update_dpp(
        __float_as_int(old), __float_as_int(src), 0x138, 0xf, 0xf, false));
}

// full-wave rotate: lane i gets src[(i-1)&63] (lane 0 <- lane 63). [HW-verified]
__device__ __forceinline__ float dpp_ror1(float src) {
    return __int_as_float(__builtin_amdgcn_update_dpp(
        0, __float_as_int(src), 0x13C, 0xf, 0xf, false));
}

__device__ __forceinline__ float lane_bcast(float v, int l) {
    return __int_as_float(__builtin_amdgcn_readlane(__float_as_int(v), l));
}

// ---------------------------------------------------------------------------
// Kernel 1 (v10, unchanged): 128x128-tile pairdist, diag-grouped output.
// ---------------------------------------------------------------------------
#define XST  132              // [k][i] stride for 128-wide tiles
#define DST  260              // diag row stride (aligned reads, 2-way writes)

__global__ __launch_bounds__(256) void pairdist128(
    const float* __restrict__ X, const float* __restrict__ Y,
    float* __restrict__ Dd)
{
    const int b   = blockIdx.z;
    const int i0  = blockIdx.y * 128;
    const int j0  = blockIdx.x * 128;
    const int tid = threadIdx.x;

    __shared__ __align__(16) float smem[2 * 64 * XST];  // XsT|YsT, then diag
    __shared__ float x2s[128], y2s[128];
    float* XsT  = smem;              // [k][i], i < 128
    float* YsT  = smem + 64 * XST;   // [k][j], j < 128
    float* diag = smem;              // [il][p_local], stride DST (aliased)

    const float* Xb = X + ((size_t)b * S + i0) * 64;
    const float* Yb = Y + ((size_t)b * S + j0) * 64;

    // stage 128 rows x 64 dims of X and Y, transposed to [k][row]
#pragma unroll
    for (int c = 0; c < 8; ++c) {
        int idx = c * 1024 + tid * 4;
        int row = idx >> 6;          // 0..127
        int k   = idx & 63;          // multiple of 4
        float4 vx = *(const float4*)(Xb + (size_t)row * 64 + k);
        float4 vy = *(const float4*)(Yb + (size_t)row * 64 + k);
        XsT[(k + 0) * XST + row] = vx.x; XsT[(k + 1) * XST + row] = vx.y;
        XsT[(k + 2) * XST + row] = vx.z; XsT[(k + 3) * XST + row] = vx.w;
        YsT[(k + 0) * XST + row] = vy.x; YsT[(k + 1) * XST + row] = vy.y;
        YsT[(k + 2) * XST + row] = vy.z; YsT[(k + 3) * XST + row] = vy.w;
    }
    __syncthreads();

    // row/col squared norms (same fmaf chain as before -> bit-exact)
    if (tid < 128) {
        float s = 0.f;
#pragma unroll 8
        for (int k = 0; k < 64; ++k) { float v = XsT[k * XST + tid]; s = fmaf(v, v, s); }
        x2s[tid] = s;
    } else {
        int r = tid - 128;
        float s = 0.f;
#pragma unroll 8
        for (int k = 0; k < 64; ++k) { float v = YsT[k * XST + r]; s = fmaf(v, v, s); }
        y2s[r] = s;
    }
    __syncthreads();

    const int tx = tid & 15;
    const int ty = tid >> 4;
    float acc[8][8] = {};
#pragma unroll 2
    for (int k = 0; k < 64; ++k) {
        float4 a0 = *(const float4*)&XsT[k * XST + ty * 4];
        float4 a1 = *(const float4*)&XsT[k * XST + 64 + ty * 4];
        float4 b0 = *(const float4*)&YsT[k * XST + tx * 8];
        float4 b1 = *(const float4*)&YsT[k * XST + tx * 8 + 4];
        float av[8] = {a0.x, a0.y, a0.z, a0.w, a1.x, a1.y, a1.z, a1.w};
        float bv[8] = {b0.x, b0.y, b0.z, b0.w, b1.x, b1.y, b1.z, b1.w};
#pragma unroll
        for (int r = 0; r < 8; ++r)
#pragma unroll
            for (int c = 0; c < 8; ++c)
                acc[r][c] = fmaf(av[r], bv[c], acc[r][c]);
    }

    // epilogue in place: acc[r][c] -> D value (same expression as before)
    float xr[8], yc[8];
#pragma unroll
    for (int r = 0; r < 4; ++r) { xr[r] = x2s[ty * 4 + r]; xr[4 + r] = x2s[64 + ty * 4 + r]; }
#pragma unroll
    for (int c = 0; c < 8; ++c) yc[c] = y2s[tx * 8 + c];
#pragma unroll
    for (int r = 0; r < 8; ++r)
#pragma unroll
        for (int c = 0; c < 8; ++c)
            acc[r][c] = xr[r] + yc[c] - 2.0f * acc[r][c];

    const int w     = tid >> 6;
    const int il    = tid & 63;
    const int gbase = (i0 + j0) >> 2;
    float* dstB = Dd + (size_t)b * (NGRP * S * 4);

#pragma unroll
    for (int pass = 0; pass < 2; ++pass) {
        __syncthreads();   // XsT/YsT (or previous diag) reads done

        // write this pass's 64 rows into diag[il][p_local]
#pragma unroll
        for (int r = 0; r < 4; ++r) {
            int ilw  = ty * 4 + r;                 // LDS row slot
            int iLoc = pass * 64 + ilw;            // tile-local row
            int base = ilw * DST + iLoc + tx * 8;  // p_local = iLoc + tx*8 + c
#pragma unroll
            for (int c = 0; c < 8; ++c)
                diag[base + c] = acc[pass * 4 + r][c];
        }
        __syncthreads();

        // store phase: wave w -> groups gl = w + 4t; lane = row il
        const int t0 = pass ? 4 : 0;               // B: gl >= 16
        const int t1 = pass ? 16 : 12;             // A: gl <= 47
        const int iLoc = pass * 64 + il;
        for (int t = t0; t < t1; ++t) {
            int gl = w + 4 * t;
            float4 v = *(const float4*)&diag[il * DST + 4 * gl];
            int joff = 4 * gl - iLoc;              // j_local of component 0
            size_t base = ((size_t)(gbase + gl) * S + (i0 + iLoc)) * 4;
            if (joff >= 0 && joff <= 124) {
                *(float4*)(dstB + base) = v;
            } else {
                if ((unsigned)(joff + 0) < 128u) dstB[base + 0] = v.x;
                if ((unsigned)(joff + 1) < 128u) dstB[base + 1] = v.y;
                if ((unsigned)(joff + 2) < 128u) dstB[base + 2] = v.z;
                if ((unsigned)(joff + 3) < 128u) dstB[base + 3] = v.w;
            }
        }
    }
}

// ---------------------------------------------------------------------------
// Kernel 2 (v12-fixed): 32-diagonal-window staggered soft-DTW DP.
// 8 waves x 64-row strips + SIMD pairing (v5-verified), windows of 32
// diagonals: stagger 3 supers, 18 windows/strip, wall = (3*7+18)*32 = 1248
// steps vs v5's 1472 (-15%).
// Collection geometry (bug in first attempt, now derived from DPP):
// insert at step s -> same-step ror puts it at lane 0 -> after the window's
// remaining 31-s rotations it sits at lane 31-s. So the CURRENT window
// occupies lanes 0..31 (step s at lane 31-s); lanes 32..63 hold the stale
// previous window. Publish lanes < 32 (ring[l] = step 31-l); the window's
// last value (step 31) is at lane 0 -> last_prev = bcast(tacc, 0).
// Consumer at step k consumes rotating tshift's original lane 64-k =
// ring[32-k] = step k-1 (k>=1); step 0 consumes lane 0 = extra = producer
// window na+1's last. Timing: consumer window na at super n reads parity
// (n-1)&1, published by producer (strip-1) completing window na+2 — and
// column check: consumer needs col 32*na+k on diag p-1 = producer window
// na+2 step k-1 exactly. Head preds windows 0-1 (lane<=k, lane<=32+k),
// tail 16-17 (lane>k, lane>32+k); output R[511][511] = strip 7 window 17
// step 30 (p=1022, even bank rE), frozen through the dead p=1023 step.
// Per-cell FP expression identical to v1-v11 -> bit-exact.
// ---------------------------------------------------------------------------
__global__ __launch_bounds__(512) void softdtw_dp_w32(
    const float* __restrict__ Dd, float* __restrict__ out)
{
    const int b     = blockIdx.x;
    const int tid   = threadIdx.x;
    const int w     = tid >> 6;
    const int lane  = tid & 63;
    const int strip = 2 * (w & 3) + (w >> 2);   // SIMD s hosts strips 2s, 2s+1

    __shared__ float ring[2][7][32];   // [parity][producer strip][slot]
    __shared__ float extraS[2][7];     // previous window's last value

    const float4* __restrict__ Dbat =
        (const float4*)(Dd + (size_t)b * (NGRP * S * 4));

    const int  i0     = 64 * strip + lane;   // this lane's matrix row
    const bool is63   = (lane == 63);
    const int  rdslot = lane & 31;           // lanes>=33: slot lane-32

    float rE = INFF, rO = INFF;        // even-diag bank, odd-diag bank
    float up_prev = INFF, tshift = INFF, tacc = INFF, last_prev = INFF;
    float4 Q[4];
    int qg = 0;                        // group consumed by current GITER

    // one cell: PW = write bank (diag p-2 -> p), CU = other bank (diag p-1)
#define CELL1(PW, CU, qc, PREDM, kk)                                     \
    {                                                                    \
        float up = dpp_shr1(CU, tshift);   /* lane0 <- stream(p-1) */    \
        tshift = dpp_ror1(tshift);                                       \
        float dd = up_prev, lf = CU;                                     \
        float mn = fminf(up, fminf(dd, lf));                             \
        float e  = __expf(mn - dd) + __expf(mn - up) + __expf(mn - lf);  \
        float val = (qc) + (mn - __logf(e));                             \
        PREDM(kk, PW)                                                    \
        PW = val;                                                        \
        tacc = dpp_ror1(is63 ? PW : tacc);                               \
        up_prev = up;                                                    \
    }

#define P_NONE(k, PW)
#define P_H0(k, PW)  val = (lane <= (k))      ? val : PW;   /* win 0  */
#define P_H1(k, PW)  val = (lane <= 32 + (k)) ? val : PW;   /* win 1  */
#define P_T0(k, PW)  val = (lane >  (k))      ? val : PW;   /* win 16 */
#define P_T1(k, PW)  val = (lane >  32 + (k)) ? val : PW;   /* win 17 */

    // 4 steps = one D group (window start p0 multiple of 4 -> E,O,E,O static)
#define GITER1(Qi, PREDM, kk)                                            \
    {                                                                    \
        float4 q = Q[Qi];                                                \
        int gq = qg + 4; gq = (gq > 255) ? 255 : gq;                     \
        Q[Qi] = *(Dbat + (size_t)gq * S + i0);                           \
        qg += 1;                                                         \
        CELL1(rE, rO, q.x, PREDM, (kk) + 0)                              \
        CELL1(rO, rE, q.y, PREDM, (kk) + 1)                              \
        CELL1(rE, rO, q.z, PREDM, (kk) + 2)                              \
        CELL1(rO, rE, q.w, PREDM, (kk) + 3)                              \
    }

    // full 32-step window with predicate macro (8 groups)
#define WIN(PREDM)                                                       \
    {                                                                    \
        GITER1(0, PREDM, 0)   GITER1(1, PREDM, 4)                        \
        GITER1(2, PREDM, 8)   GITER1(3, PREDM, 12)                       \
        GITER1(0, PREDM, 16)  GITER1(1, PREDM, 20)                       \
        GITER1(2, PREDM, 24)  GITER1(3, PREDM, 28)                       \
    }

    for (int n = 0; n < 39; ++n) {
        const int na = n - 3 * strip;          // window index for this strip
        if (0 <= na && na < 18) {
            if (na == 0) {                     // strip-run start: seed + queue
                up_prev = (strip == 0) ? 0.0f : INFF;   // corner / INF wall
                qg = 16 * strip;
#pragma unroll
                for (int i = 0; i < 4; ++i)
                    Q[i] = *(Dbat + (size_t)(qg + i) * S + i0);
            }
            if (strip > 0) {                   // boundary stream for window
                float bv = ring[(n - 1) & 1][strip - 1][rdslot];
                float ex = extraS[(n - 1) & 1][strip - 1];
                tshift = (lane == 0) ? ex : bv;
            } else {
                tshift = INFF;                 // R[-1][*] wall for strip 0
            }

            if (na == 0)       { WIN(P_H0) }   // head: lane <= k
            else if (na == 1)  { WIN(P_H1) }   // head: lane <= 32+k
            else if (na == 16) { WIN(P_T0) }   // tail: lane > k
            else if (na == 17) { WIN(P_T1) }   // tail: lane > 32+k
            else {                             // hot path (14 windows)
#pragma unroll 1
                for (int it = 0; it < 2; ++it) {
                    GITER1(0, P_NONE, 0) GITER1(1, P_NONE, 0)
                    GITER1(2, P_NONE, 0) GITER1(3, P_NONE, 0)
                }
            }

            if (strip < 7) {                   // publish window block + extra
                if (lane < 32)  ring[n & 1][strip][lane] = tacc; // step 31-lane
                if (lane == 0)  extraS[n & 1][strip] = last_prev;
                last_prev = lane_bcast(tacc, 0);   // this window's last value
            }
        }
        __syncthreads();
    }
#undef WIN
#undef GITER1
#undef P_T1
#undef P_T0
#undef P_H1
#undef P_H0
#undef P_NONE
#undef CELL1

    // R[511][511]: strip 7 (wave 7), lane 63, p = 1022 (even bank),
    // computed at window 17 step 30 and frozen by the tail predicate.
    if (tid == 511) out[b] = rE;
}

// ---------------------------------------------------------------------------
extern "C" void kernel_launch(void* const* d_in, const int* in_sizes, int n_in,
                              void* d_out, int out_size, void* d_ws, size_t ws_size,
                              hipStream_t stream)
{
    const float* X = (const float*)d_in[0];
    const float* Y = (const float*)d_in[1];
    float* out = (float*)d_out;
    float* Dd  = (float*)d_ws;   // 32 * 256*512*4 floats = 64 MiB

    dim3 g1(S / 128, S / 128, BATCH);
    pairdist128<<<g1, 256, 0, stream>>>(X, Y, Dd);

    softdtw_dp_w32<<<BATCH, 512, 0, stream>>>(Dd, out);
}

// Round 14
// 199.304 us; speedup vs baseline: 1.5129x; 1.2514x over previous
//
#include <hip/hip_runtime.h>
#include <math.h>

#define S      512
#define BATCH  32
#define NGRP   256           // diagonal groups of 4: p in [0,1023) -> p>>2 in [0,256)
#define INFF   __builtin_huge_valf()
#define L2E    1.4426950408889634f   // log2(e)

// raw hardware transcendentals: v_exp_f32 = 2^x, v_log_f32 = log2(x)
#if __has_builtin(__builtin_amdgcn_exp2f)
#define EXP2F(x) __builtin_amdgcn_exp2f(x)
#else
#define EXP2F(x) exp2f(x)
#endif
#if __has_builtin(__builtin_amdgcn_logf)
#define LOG2F(x) __builtin_amdgcn_logf(x)
#else
#define LOG2F(x) __log2f(x)
#endif

// wave-wide shift-up-by-1 via DPP wave_shr:1 (VALU, no DS pipe).
// lane i gets src[i-1]; lane 0 gets old's lane-0 value (bound_ctrl=false). [HW-verified]
__device__ __forceinline__ float dpp_shr1(float src, float old) {
    return __int_as_float(__builtin_amdgcn_update_dpp(
        __float_as_int(old), __float_as_int(src), 0x138, 0xf, 0xf, false));
}

// full-wave rotate: lane i gets src[(i-1)&63] (lane 0 <- lane 63). [HW-verified]
__device__ __forceinline__ float dpp_ror1(float src) {
    return __int_as_float(__builtin_amdgcn_update_dpp(
        0, __float_as_int(src), 0x13C, 0xf, 0xf, false));
}

__device__ __forceinline__ float lane_bcast(float v, int l) {
    return __int_as_float(__builtin_amdgcn_readlane(__float_as_int(v), l));
}

// ---------------------------------------------------------------------------
// Kernel 1 (v13): 128x128-tile pairdist, diag-grouped output, now emitting
// D~ = D * log2(e) so the DP can run entirely in base-2 (v_exp/v_log raw).
// ---------------------------------------------------------------------------
#define XST  132              // [k][i] stride for 128-wide tiles
#define DST  260              // diag row stride (aligned reads, 2-way writes)

__global__ __launch_bounds__(256) void pairdist128(
    const float* __restrict__ X, const float* __restrict__ Y,
    float* __restrict__ Dd)
{
    const int b   = blockIdx.z;
    const int i0  = blockIdx.y * 128;
    const int j0  = blockIdx.x * 128;
    const int tid = threadIdx.x;

    __shared__ __align__(16) float smem[2 * 64 * XST];  // XsT|YsT, then diag
    __shared__ float x2s[128], y2s[128];
    float* XsT  = smem;              // [k][i], i < 128
    float* YsT  = smem + 64 * XST;   // [k][j], j < 128
    float* diag = smem;              // [il][p_local], stride DST (aliased)

    const float* Xb = X + ((size_t)b * S + i0) * 64;
    const float* Yb = Y + ((size_t)b * S + j0) * 64;

    // stage 128 rows x 64 dims of X and Y, transposed to [k][row]
#pragma unroll
    for (int c = 0; c < 8; ++c) {
        int idx = c * 1024 + tid * 4;
        int row = idx >> 6;          // 0..127
        int k   = idx & 63;          // multiple of 4
        float4 vx = *(const float4*)(Xb + (size_t)row * 64 + k);
        float4 vy = *(const float4*)(Yb + (size_t)row * 64 + k);
        XsT[(k + 0) * XST + row] = vx.x; XsT[(k + 1) * XST + row] = vx.y;
        XsT[(k + 2) * XST + row] = vx.z; XsT[(k + 3) * XST + row] = vx.w;
        YsT[(k + 0) * XST + row] = vy.x; YsT[(k + 1) * XST + row] = vy.y;
        YsT[(k + 2) * XST + row] = vy.z; YsT[(k + 3) * XST + row] = vy.w;
    }
    __syncthreads();

    // row/col squared norms
    if (tid < 128) {
        float s = 0.f;
#pragma unroll 8
        for (int k = 0; k < 64; ++k) { float v = XsT[k * XST + tid]; s = fmaf(v, v, s); }
        x2s[tid] = s;
    } else {
        int r = tid - 128;
        float s = 0.f;
#pragma unroll 8
        for (int k = 0; k < 64; ++k) { float v = YsT[k * XST + r]; s = fmaf(v, v, s); }
        y2s[r] = s;
    }
    __syncthreads();

    const int tx = tid & 15;
    const int ty = tid >> 4;
    float acc[8][8] = {};
#pragma unroll 2
    for (int k = 0; k < 64; ++k) {
        float4 a0 = *(const float4*)&XsT[k * XST + ty * 4];
        float4 a1 = *(const float4*)&XsT[k * XST + 64 + ty * 4];
        float4 b0 = *(const float4*)&YsT[k * XST + tx * 8];
        float4 b1 = *(const float4*)&YsT[k * XST + tx * 8 + 4];
        float av[8] = {a0.x, a0.y, a0.z, a0.w, a1.x, a1.y, a1.z, a1.w};
        float bv[8] = {b0.x, b0.y, b0.z, b0.w, b1.x, b1.y, b1.z, b1.w};
#pragma unroll
        for (int r = 0; r < 8; ++r)
#pragma unroll
            for (int c = 0; c < 8; ++c)
                acc[r][c] = fmaf(av[r], bv[c], acc[r][c]);
    }

    // epilogue: D = xr + yc - 2*acc, then scale to base-2 (D~ = D * log2 e)
    float xr[8], yc[8];
#pragma unroll
    for (int r = 0; r < 4; ++r) { xr[r] = x2s[ty * 4 + r]; xr[4 + r] = x2s[64 + ty * 4 + r]; }
#pragma unroll
    for (int c = 0; c < 8; ++c) yc[c] = y2s[tx * 8 + c];
#pragma unroll
    for (int r = 0; r < 8; ++r)
#pragma unroll
        for (int c = 0; c < 8; ++c)
            acc[r][c] = (xr[r] + yc[c] - 2.0f * acc[r][c]) * L2E;

    const int w     = tid >> 6;
    const int il    = tid & 63;
    const int gbase = (i0 + j0) >> 2;
    float* dstB = Dd + (size_t)b * (NGRP * S * 4);

#pragma unroll
    for (int pass = 0; pass < 2; ++pass) {
        __syncthreads();   // XsT/YsT (or previous diag) reads done

        // write this pass's 64 rows into diag[il][p_local]
#pragma unroll
        for (int r = 0; r < 4; ++r) {
            int ilw  = ty * 4 + r;                 // LDS row slot
            int iLoc = pass * 64 + ilw;            // tile-local row
            int base = ilw * DST + iLoc + tx * 8;  // p_local = iLoc + tx*8 + c
#pragma unroll
            for (int c = 0; c < 8; ++c)
                diag[base + c] = acc[pass * 4 + r][c];
        }
        __syncthreads();

        // store phase: wave w -> groups gl = w + 4t; lane = row il
        const int t0 = pass ? 4 : 0;               // B: gl >= 16
        const int t1 = pass ? 16 : 12;             // A: gl <= 47
        const int iLoc = pass * 64 + il;
        for (int t = t0; t < t1; ++t) {
            int gl = w + 4 * t;
            float4 v = *(const float4*)&diag[il * DST + 4 * gl];
            int joff = 4 * gl - iLoc;              // j_local of component 0
            size_t base = ((size_t)(gbase + gl) * S + (i0 + iLoc)) * 4;
            if (joff >= 0 && joff <= 124) {
                *(float4*)(dstB + base) = v;
            } else {
                if ((unsigned)(joff + 0) < 128u) dstB[base + 0] = v.x;
                if ((unsigned)(joff + 1) < 128u) dstB[base + 1] = v.y;
                if ((unsigned)(joff + 2) < 128u) dstB[base + 2] = v.z;
                if ((unsigned)(joff + 3) < 128u) dstB[base + 3] = v.w;
            }
        }
    }
}

// ---------------------------------------------------------------------------
// Kernel 2 (v13): base-2 32-diagonal-window staggered soft-DTW DP.
// Identical structure/protocol to the verified v12-fixed (ring slot = lane,
// step 31-lane; extra = window-last via lane 0; stagger 3; 39 supers), but
// the recurrence runs scaled by log2(e): with R~ = R*log2e, D~ = D*log2e,
//   R~ = D~ + m~ - log2( 2^{m~-dd~} + 2^{m~-up~} + 2^{m~-lf~} )
// which uses the RAW v_exp_f32/v_log_f32 (2^x / log2) — removing the 4
// correction multiplies per cell that __expf/__logf carry (2 of them on the
// serial chain). Seeds 0/INF are fixed points of the scaling; INF wall and
// predication semantics unchanged. Output un-scaled once: R = R~ * ln2.
// NOT bit-exact vs reference (~1 ulp/step drift); harness threshold 1285.
// ---------------------------------------------------------------------------
__global__ __launch_bounds__(512) void softdtw_dp_w32(
    const float* __restrict__ Dd, float* __restrict__ out)
{
    const int b     = blockIdx.x;
    const int tid   = threadIdx.x;
    const int w     = tid >> 6;
    const int lane  = tid & 63;
    const int strip = 2 * (w & 3) + (w >> 2);   // SIMD s hosts strips 2s, 2s+1

    __shared__ float ring[2][7][32];   // [parity][producer strip][slot]
    __shared__ float extraS[2][7];     // previous window's last value

    const float4* __restrict__ Dbat =
        (const float4*)(Dd + (size_t)b * (NGRP * S * 4));

    const int  i0     = 64 * strip + lane;   // this lane's matrix row
    const bool is63   = (lane == 63);
    const int  rdslot = lane & 31;           // lanes>=33: slot lane-32

    float rE = INFF, rO = INFF;        // even-diag bank, odd-diag bank
    float up_prev = INFF, tshift = INFF, tacc = INFF, last_prev = INFF;
    float4 Q[4];
    int qg = 0;                        // group consumed by current GITER

    // one cell: PW = write bank (diag p-2 -> p), CU = other bank (diag p-1)
#define CELL1(PW, CU, qc, PREDM, kk)                                     \
    {                                                                    \
        float up = dpp_shr1(CU, tshift);   /* lane0 <- stream(p-1) */    \
        tshift = dpp_ror1(tshift);                                       \
        float dd = up_prev, lf = CU;                                     \
        float mn = fminf(up, fminf(dd, lf));                             \
        float e  = EXP2F(mn - dd) + EXP2F(mn - up) + EXP2F(mn - lf);     \
        float val = (qc) + (mn - LOG2F(e));                              \
        PREDM(kk, PW)                                                    \
        PW = val;                                                        \
        tacc = dpp_ror1(is63 ? PW : tacc);                               \
        up_prev = up;                                                    \
    }

#define P_NONE(k, PW)
#define P_H0(k, PW)  val = (lane <= (k))      ? val : PW;   /* win 0  */
#define P_H1(k, PW)  val = (lane <= 32 + (k)) ? val : PW;   /* win 1  */
#define P_T0(k, PW)  val = (lane >  (k))      ? val : PW;   /* win 16 */
#define P_T1(k, PW)  val = (lane >  32 + (k)) ? val : PW;   /* win 17 */

    // 4 steps = one D group (window start p0 multiple of 4 -> E,O,E,O static)
#define GITER1(Qi, PREDM, kk)                                            \
    {                                                                    \
        float4 q = Q[Qi];                                                \
        int gq = qg + 4; gq = (gq > 255) ? 255 : gq;                     \
        Q[Qi] = *(Dbat + (size_t)gq * S + i0);                           \
        qg += 1;                                                         \
        CELL1(rE, rO, q.x, PREDM, (kk) + 0)                              \
        CELL1(rO, rE, q.y, PREDM, (kk) + 1)                              \
        CELL1(rE, rO, q.z, PREDM, (kk) + 2)                              \
        CELL1(rO, rE, q.w, PREDM, (kk) + 3)                              \
    }

    // full 32-step window with predicate macro (8 groups)
#define WIN(PREDM)                                                       \
    {                                                                    \
        GITER1(0, PREDM, 0)   GITER1(1, PREDM, 4)                        \
        GITER1(2, PREDM, 8)   GITER1(3, PREDM, 12)                       \
        GITER1(0, PREDM, 16)  GITER1(1, PREDM, 20)                       \
        GITER1(2, PREDM, 24)  GITER1(3, PREDM, 28)                       \
    }

    for (int n = 0; n < 39; ++n) {
        const int na = n - 3 * strip;          // window index for this strip
        if (0 <= na && na < 18) {
            if (na == 0) {                     // strip-run start: seed + queue
                up_prev = (strip == 0) ? 0.0f : INFF;   // corner / INF wall
                qg = 16 * strip;
#pragma unroll
                for (int i = 0; i < 4; ++i)
                    Q[i] = *(Dbat + (size_t)(qg + i) * S + i0);
            }
            if (strip > 0) {                   // boundary stream for window
                float bv = ring[(n - 1) & 1][strip - 1][rdslot];
                float ex = extraS[(n - 1) & 1][strip - 1];
                tshift = (lane == 0) ? ex : bv;
            } else {
                tshift = INFF;                 // R[-1][*] wall for strip 0
            }

            if (na == 0)       { WIN(P_H0) }   // head: lane <= k
            else if (na == 1)  { WIN(P_H1) }   // head: lane <= 32+k
            else if (na == 16) { WIN(P_T0) }   // tail: lane > k
            else if (na == 17) { WIN(P_T1) }   // tail: lane > 32+k
            else {                             // hot path (14 windows)
#pragma unroll 1
                for (int it = 0; it < 2; ++it) {
                    GITER1(0, P_NONE, 0) GITER1(1, P_NONE, 0)
                    GITER1(2, P_NONE, 0) GITER1(3, P_NONE, 0)
                }
            }

            if (strip < 7) {                   // publish window block + extra
                if (lane < 32)  ring[n & 1][strip][lane] = tacc; // step 31-lane
                if (lane == 0)  extraS[n & 1][strip] = last_prev;
                last_prev = lane_bcast(tacc, 0);   // this window's last value
            }
        }
        __syncthreads();
    }
#undef WIN
#undef GITER1
#undef P_T1
#undef P_T0
#undef P_H1
#undef P_H0
#undef P_NONE
#undef CELL1

    // R[511][511]: strip 7 (wave 7), lane 63, p = 1022 (even bank),
    // computed at window 17 step 30 and frozen by the tail predicate.
    // Un-scale from base-2 once: R = R~ * ln2.
    if (tid == 511) out[b] = (float)((double)rE * 0.6931471805599453);
}

// ---------------------------------------------------------------------------
extern "C" void kernel_launch(void* const* d_in, const int* in_sizes, int n_in,
                              void* d_out, int out_size, void* d_ws, size_t ws_size,
                              hipStream_t stream)
{
    const float* X = (const float*)d_in[0];
    const float* Y = (const float*)d_in[1];
    float* out = (float*)d_out;
    float* Dd  = (float*)d_ws;   // 32 * 256*512*4 floats = 64 MiB

    dim3 g1(S / 128, S / 128, BATCH);
    pairdist128<<<g1, 256, 0, stream>>>(X, Y, Dd);

    softdtw_dp_w32<<<BATCH, 512, 0, stream>>>(Dd, out);
}

// Round 15
// 194.560 us; speedup vs baseline: 1.5498x; 1.0244x over previous
//
#include <hip/hip_runtime.h>
#include <math.h>

#define S      512
#define BATCH  32
#define NGRP   256           // diagonal groups of 4: p in [0,1023) -> p>>2 in [0,256)
#define INFF   __builtin_huge_valf()
#define L2E    1.4426950408889634f   // log2(e)

// raw hardware transcendentals: v_exp_f32 = 2^x, v_log_f32 = log2(x)
#if __has_builtin(__builtin_amdgcn_exp2f)
#define EXP2F(x) __builtin_amdgcn_exp2f(x)
#else
#define EXP2F(x) exp2f(x)
#endif
#if __has_builtin(__builtin_amdgcn_logf)
#define LOG2F(x) __builtin_amdgcn_logf(x)
#else
#define LOG2F(x) __log2f(x)
#endif

// wave-wide shift-up-by-1 via DPP wave_shr:1 (VALU, no DS pipe).
// lane i gets src[i-1]; lane 0 gets old's lane-0 value (bound_ctrl=false). [HW-verified]
__device__ __forceinline__ float dpp_shr1(float src, float old) {
    return __int_as_float(__builtin_amdgcn_update_dpp(
        __float_as_int(old), __float_as_int(src), 0x138, 0xf, 0xf, false));
}

// full-wave rotate: lane i gets src[(i-1)&63] (lane 0 <- lane 63). [HW-verified]
__device__ __forceinline__ float dpp_ror1(float src) {
    return __int_as_float(__builtin_amdgcn_update_dpp(
        0, __float_as_int(src), 0x13C, 0xf, 0xf, false));
}

__device__ __forceinline__ float lane_bcast(float v, int l) {
    return __int_as_float(__builtin_amdgcn_readlane(__float_as_int(v), l));
}

// ---------------------------------------------------------------------------
// Kernel 1 (v13, unchanged): 128x128-tile pairdist, diag-grouped output,
// emitting D~ = D * log2(e) for the base-2 DP.
// ---------------------------------------------------------------------------
#define XST  132              // [k][i] stride for 128-wide tiles
#define DST  260              // diag row stride (aligned reads, 2-way writes)

__global__ __launch_bounds__(256) void pairdist128(
    const float* __restrict__ X, const float* __restrict__ Y,
    float* __restrict__ Dd)
{
    const int b   = blockIdx.z;
    const int i0  = blockIdx.y * 128;
    const int j0  = blockIdx.x * 128;
    const int tid = threadIdx.x;

    __shared__ __align__(16) float smem[2 * 64 * XST];  // XsT|YsT, then diag
    __shared__ float x2s[128], y2s[128];
    float* XsT  = smem;              // [k][i], i < 128
    float* YsT  = smem + 64 * XST;   // [k][j], j < 128
    float* diag = smem;              // [il][p_local], stride DST (aliased)

    const float* Xb = X + ((size_t)b * S + i0) * 64;
    const float* Yb = Y + ((size_t)b * S + j0) * 64;

    // stage 128 rows x 64 dims of X and Y, transposed to [k][row]
#pragma unroll
    for (int c = 0; c < 8; ++c) {
        int idx = c * 1024 + tid * 4;
        int row = idx >> 6;          // 0..127
        int k   = idx & 63;          // multiple of 4
        float4 vx = *(const float4*)(Xb + (size_t)row * 64 + k);
        float4 vy = *(const float4*)(Yb + (size_t)row * 64 + k);
        XsT[(k + 0) * XST + row] = vx.x; XsT[(k + 1) * XST + row] = vx.y;
        XsT[(k + 2) * XST + row] = vx.z; XsT[(k + 3) * XST + row] = vx.w;
        YsT[(k + 0) * XST + row] = vy.x; YsT[(k + 1) * XST + row] = vy.y;
        YsT[(k + 2) * XST + row] = vy.z; YsT[(k + 3) * XST + row] = vy.w;
    }
    __syncthreads();

    // row/col squared norms
    if (tid < 128) {
        float s = 0.f;
#pragma unroll 8
        for (int k = 0; k < 64; ++k) { float v = XsT[k * XST + tid]; s = fmaf(v, v, s); }
        x2s[tid] = s;
    } else {
        int r = tid - 128;
        float s = 0.f;
#pragma unroll 8
        for (int k = 0; k < 64; ++k) { float v = YsT[k * XST + r]; s = fmaf(v, v, s); }
        y2s[r] = s;
    }
    __syncthreads();

    const int tx = tid & 15;
    const int ty = tid >> 4;
    float acc[8][8] = {};
#pragma unroll 2
    for (int k = 0; k < 64; ++k) {
        float4 a0 = *(const float4*)&XsT[k * XST + ty * 4];
        float4 a1 = *(const float4*)&XsT[k * XST + 64 + ty * 4];
        float4 b0 = *(const float4*)&YsT[k * XST + tx * 8];
        float4 b1 = *(const float4*)&YsT[k * XST + tx * 8 + 4];
        float av[8] = {a0.x, a0.y, a0.z, a0.w, a1.x, a1.y, a1.z, a1.w};
        float bv[8] = {b0.x, b0.y, b0.z, b0.w, b1.x, b1.y, b1.z, b1.w};
#pragma unroll
        for (int r = 0; r < 8; ++r)
#pragma unroll
            for (int c = 0; c < 8; ++c)
                acc[r][c] = fmaf(av[r], bv[c], acc[r][c]);
    }

    // epilogue: D = xr + yc - 2*acc, then scale to base-2 (D~ = D * log2 e)
    float xr[8], yc[8];
#pragma unroll
    for (int r = 0; r < 4; ++r) { xr[r] = x2s[ty * 4 + r]; xr[4 + r] = x2s[64 + ty * 4 + r]; }
#pragma unroll
    for (int c = 0; c < 8; ++c) yc[c] = y2s[tx * 8 + c];
#pragma unroll
    for (int r = 0; r < 8; ++r)
#pragma unroll
        for (int c = 0; c < 8; ++c)
            acc[r][c] = (xr[r] + yc[c] - 2.0f * acc[r][c]) * L2E;

    const int w     = tid >> 6;
    const int il    = tid & 63;
    const int gbase = (i0 + j0) >> 2;
    float* dstB = Dd + (size_t)b * (NGRP * S * 4);

#pragma unroll
    for (int pass = 0; pass < 2; ++pass) {
        __syncthreads();   // XsT/YsT (or previous diag) reads done

        // write this pass's 64 rows into diag[il][p_local]
#pragma unroll
        for (int r = 0; r < 4; ++r) {
            int ilw  = ty * 4 + r;                 // LDS row slot
            int iLoc = pass * 64 + ilw;            // tile-local row
            int base = ilw * DST + iLoc + tx * 8;  // p_local = iLoc + tx*8 + c
#pragma unroll
            for (int c = 0; c < 8; ++c)
                diag[base + c] = acc[pass * 4 + r][c];
        }
        __syncthreads();

        // store phase: wave w -> groups gl = w + 4t; lane = row il
        const int t0 = pass ? 4 : 0;               // B: gl >= 16
        const int t1 = pass ? 16 : 12;             // A: gl <= 47
        const int iLoc = pass * 64 + il;
        for (int t = t0; t < t1; ++t) {
            int gl = w + 4 * t;
            float4 v = *(const float4*)&diag[il * DST + 4 * gl];
            int joff = 4 * gl - iLoc;              // j_local of component 0
            size_t base = ((size_t)(gbase + gl) * S + (i0 + iLoc)) * 4;
            if (joff >= 0 && joff <= 124) {
                *(float4*)(dstB + base) = v;
            } else {
                if ((unsigned)(joff + 0) < 128u) dstB[base + 0] = v.x;
                if ((unsigned)(joff + 1) < 128u) dstB[base + 1] = v.y;
                if ((unsigned)(joff + 2) < 128u) dstB[base + 2] = v.z;
                if ((unsigned)(joff + 3) < 128u) dstB[base + 3] = v.w;
            }
        }
    }
}

// ---------------------------------------------------------------------------
// Kernel 2 (v14): base-2, 16-diagonal-window staggered soft-DTW DP.
// Same 8-wave x 64-row-strip skeleton + base-2 cell as v13 (verified), with
// W = 16: producer dependency becomes window na+4 (floor((63+16na+k)/16)),
// so stagger 5, 36 windows/strip, 71 supers -> wall = 71*16 = 1136 steps
// vs 1248 (-9%), +32 barriers.
// Protocol (column-verified): consumer window na step 0 <- extraS =
// producer window na+3's last (published alongside window na+4's block at
// super n-1: producer super index 4 -> block win4 + extra win3 ✓); steps
// k=1..15 <- ring slot (lane-48) for original lanes 64-k in [49,63] = step
// k-1 of window na+4 (tacc: current window at lanes 0..15, step s at lane
// 15-s; publish lanes<16; last = lane 0). Head preds windows 0-3
// (lane<=k, <=16+k, <=32+k, <=48+k); tail 32-35 (>k, >16+k, >32+k, >48+k).
// Consumer windows >=32 consume stale/absent producer data only at lane 0,
// frozen by the tail pred (j>511) -> harmless. Output: strip 7 window 35
// step 14 (p=1022 even -> rE), frozen at step 15. Same reals, same per-cell
// arithmetic as v13 -> absmax 0.0 expected.
// ---------------------------------------------------------------------------
__global__ __launch_bounds__(512) void softdtw_dp_w16(
    const float* __restrict__ Dd, float* __restrict__ out)
{
    const int b     = blockIdx.x;
    const int tid   = threadIdx.x;
    const int w     = tid >> 6;
    const int lane  = tid & 63;
    const int strip = 2 * (w & 3) + (w >> 2);   // SIMD s hosts strips 2s, 2s+1

    __shared__ float ring[2][7][16];   // [parity][producer strip][slot]
    __shared__ float extraS[2][7];     // previous window's last value

    const float4* __restrict__ Dbat =
        (const float4*)(Dd + (size_t)b * (NGRP * S * 4));

    const int  i0     = 64 * strip + lane;   // this lane's matrix row
    const bool is63   = (lane == 63);
    const int  rdslot = lane & 15;           // lanes>=49: slot lane-48

    float rE = INFF, rO = INFF;        // even-diag bank, odd-diag bank
    float up_prev = INFF, tshift = INFF, tacc = INFF, last_prev = INFF;
    float4 Q[4];
    int qg = 0;                        // group consumed by current GITER

    // one cell: PW = write bank (diag p-2 -> p), CU = other bank (diag p-1)
#define CELL1(PW, CU, qc, PREDM, kk)                                     \
    {                                                                    \
        float up = dpp_shr1(CU, tshift);   /* lane0 <- stream(p-1) */    \
        tshift = dpp_ror1(tshift);                                       \
        float dd = up_prev, lf = CU;                                     \
        float mn = fminf(up, fminf(dd, lf));                             \
        float e  = EXP2F(mn - dd) + EXP2F(mn - up) + EXP2F(mn - lf);     \
        float val = (qc) + (mn - LOG2F(e));                              \
        PREDM(kk, PW)                                                    \
        PW = val;                                                        \
        tacc = dpp_ror1(is63 ? PW : tacc);                               \
        up_prev = up;                                                    \
    }

#define P_NONE(k, PW)
#define P_H0(k, PW)  val = (lane <= (k))      ? val : PW;   /* win 0  */
#define P_H1(k, PW)  val = (lane <= 16 + (k)) ? val : PW;   /* win 1  */
#define P_H2(k, PW)  val = (lane <= 32 + (k)) ? val : PW;   /* win 2  */
#define P_H3(k, PW)  val = (lane <= 48 + (k)) ? val : PW;   /* win 3  */
#define P_T0(k, PW)  val = (lane >  (k))      ? val : PW;   /* win 32 */
#define P_T1(k, PW)  val = (lane >  16 + (k)) ? val : PW;   /* win 33 */
#define P_T2(k, PW)  val = (lane >  32 + (k)) ? val : PW;   /* win 34 */
#define P_T3(k, PW)  val = (lane >  48 + (k)) ? val : PW;   /* win 35 */

    // 4 steps = one D group (window start p0 multiple of 16 -> E,O,E,O static)
#define GITER1(Qi, PREDM, kk)                                            \
    {                                                                    \
        float4 q = Q[Qi];                                                \
        int gq = qg + 4; gq = (gq > 255) ? 255 : gq;                     \
        Q[Qi] = *(Dbat + (size_t)gq * S + i0);                           \
        qg += 1;                                                         \
        CELL1(rE, rO, q.x, PREDM, (kk) + 0)                              \
        CELL1(rO, rE, q.y, PREDM, (kk) + 1)                              \
        CELL1(rE, rO, q.z, PREDM, (kk) + 2)                              \
        CELL1(rO, rE, q.w, PREDM, (kk) + 3)                              \
    }

    // full 16-step window with predicate macro (4 groups)
#define WIN(PREDM)                                                       \
    {                                                                    \
        GITER1(0, PREDM, 0)   GITER1(1, PREDM, 4)                        \
        GITER1(2, PREDM, 8)   GITER1(3, PREDM, 12)                       \
    }

    for (int n = 0; n < 71; ++n) {
        const int na = n - 5 * strip;          // window index for this strip
        if (0 <= na && na < 36) {
            if (na == 0) {                     // strip-run start: seed + queue
                up_prev = (strip == 0) ? 0.0f : INFF;   // corner / INF wall
                qg = 16 * strip;
#pragma unroll
                for (int i = 0; i < 4; ++i)
                    Q[i] = *(Dbat + (size_t)(qg + i) * S + i0);
            }
            if (strip > 0) {                   // boundary stream for window
                float bv = ring[(n - 1) & 1][strip - 1][rdslot];
                float ex = extraS[(n - 1) & 1][strip - 1];
                tshift = (lane == 0) ? ex : bv;
            } else {
                tshift = INFF;                 // R[-1][*] wall for strip 0
            }

            if (na == 0)       { WIN(P_H0) }   // head
            else if (na == 1)  { WIN(P_H1) }
            else if (na == 2)  { WIN(P_H2) }
            else if (na == 3)  { WIN(P_H3) }
            else if (na == 32) { WIN(P_T0) }   // tail
            else if (na == 33) { WIN(P_T1) }
            else if (na == 34) { WIN(P_T2) }
            else if (na == 35) { WIN(P_T3) }
            else {                             // hot path (28 windows)
                WIN(P_NONE)
            }

            if (strip < 7) {                   // publish window block + extra
                if (lane < 16)  ring[n & 1][strip][lane] = tacc; // step 15-lane
                if (lane == 0)  extraS[n & 1][strip] = last_prev;
                last_prev = lane_bcast(tacc, 0);   // this window's last value
            }
        }
        __syncthreads();
    }
#undef WIN
#undef GITER1
#undef P_T3
#undef P_T2
#undef P_T1
#undef P_T0
#undef P_H3
#undef P_H2
#undef P_H1
#undef P_H0
#undef P_NONE
#undef CELL1

    // R[511][511]: strip 7 (wave 7), lane 63, p = 1022 (even bank),
    // computed at window 35 step 14 and frozen by the tail predicate.
    // Un-scale from base-2 once: R = R~ * ln2.
    if (tid == 511) out[b] = (float)((double)rE * 0.6931471805599453);
}

// ---------------------------------------------------------------------------
extern "C" void kernel_launch(void* const* d_in, const int* in_sizes, int n_in,
                              void* d_out, int out_size, void* d_ws, size_t ws_size,
                              hipStream_t stream)
{
    const float* X = (const float*)d_in[0];
    const float* Y = (const float*)d_in[1];
    float* out = (float*)d_out;
    float* Dd  = (float*)d_ws;   // 32 * 256*512*4 floats = 64 MiB

    dim3 g1(S / 128, S / 128, BATCH);
    pairdist128<<<g1, 256, 0, stream>>>(X, Y, Dd);

    softdtw_dp_w16<<<BATCH, 512, 0, stream>>>(Dd, out);
}